// Round 8
// baseline (222.076 us; speedup 1.0000x reference)
//
#include <hip/hip_runtime.h>
#include <hip/hip_bf16.h>

typedef __hip_bfloat16 bf16;
typedef __attribute__((ext_vector_type(4))) float f32x4;
typedef __attribute__((ext_vector_type(8))) short s16x8;
typedef __attribute__((ext_vector_type(4))) short s16x4;

#define MFMA(a, b, c) __builtin_amdgcn_mfma_f32_16x16x32_bf16((a), (b), (c), 0, 0, 0)

__device__ __forceinline__ void g2l16(const bf16* g, bf16* l) {
  __builtin_amdgcn_global_load_lds((const __attribute__((address_space(1))) void*)g,
                                   (__attribute__((address_space(3))) void*)l,
                                   16, 0, 0);
}
__device__ __forceinline__ bf16 cvt_bf(float f) { return __float2bfloat16(f); }
__device__ __forceinline__ float bf2f(bf16 h) { return __bfloat162float(h); }

// ---------------------------------------------------------------------------
// Fused prep: blocks 0-2047 weight transposes (f32 [K][N] -> bf16 [N][K]);
// blocks 2048-4095 query cvt + BOTH passthrough copies; 4096-4127 mask writes.
// ---------------------------------------------------------------------------
__global__ __launch_bounds__(256)
void prep2_k(const float* __restrict__ query, const int* __restrict__ qmask,
             const float* __restrict__ wq, const float* __restrict__ wk,
             const float* __restrict__ wv, const float* __restrict__ wo,
             const float* __restrict__ w1, const float* __restrict__ w2,
             bf16* __restrict__ wqkvT, bf16* __restrict__ woT,
             bf16* __restrict__ w1T, bf16* __restrict__ w2T,
             bf16* __restrict__ qb, float* __restrict__ out)
{
  __shared__ float tl[32][33];
  const int bid = blockIdx.x;
  if (bid < 2048) {
    const float* W; bf16* Wt; int K, N, tile;
    if (bid < 768)        { int s = bid >> 8; W = s==0?wq:(s==1?wk:wv);
                            Wt = wqkvT + s*262144; K = 512; N = 512; tile = bid & 255; }
    else if (bid < 1024)  { W = wo; Wt = woT; K = 512;  N = 512;  tile = bid - 768; }
    else if (bid < 1536)  { W = w1; Wt = w1T; K = 512;  N = 1024; tile = bid - 1024; }
    else                  { W = w2; Wt = w2T; K = 1024; N = 512;  tile = bid - 1536; }
    const int nx = N >> 5;
    const int n0 = (tile % nx) * 32, k0 = (tile / nx) * 32;
    const int tx = threadIdx.x & 31, ty = threadIdx.x >> 5;
#pragma unroll
    for (int i = 0; i < 32; i += 8)
      tl[ty + i][tx] = W[(size_t)(k0 + ty + i) * N + n0 + tx];
    __syncthreads();
#pragma unroll
    for (int i = 0; i < 32; i += 8)
      Wt[(size_t)(n0 + ty + i) * K + k0 + tx] = cvt_bf(tl[tx][ty + i]);
  } else if (bid < 4096) {
    const int i = (bid - 2048) * 2048 + threadIdx.x * 8;
    float4 a = *(const float4*)(query + i);
    float4 b = *(const float4*)(query + i + 4);
    union { bf16 h[8]; s16x8 v; } u;
    u.h[0] = cvt_bf(a.x); u.h[1] = cvt_bf(a.y); u.h[2] = cvt_bf(a.z); u.h[3] = cvt_bf(a.w);
    u.h[4] = cvt_bf(b.x); u.h[5] = cvt_bf(b.y); u.h[6] = cvt_bf(b.z); u.h[7] = cvt_bf(b.w);
    *(s16x8*)(qb + i) = u.v;
    float* o1 = out + 4202496 + i;
    float* o2 = out + 8396800 + i;
    *(float4*)o1 = a; *(float4*)(o1 + 4) = b;
    *(float4*)o2 = a; *(float4*)(o2 + 4) = b;
  } else {
    const int j = (bid - 4096) * 256 + threadIdx.x;  // 8192 total
    const float v = (float)qmask[j];
    out[4194304 + j] = v;
    out[12591104 + j] = v;
  }
}

// ---------------------------------------------------------------------------
// query f32 -> bf16 (fallback path only)
// ---------------------------------------------------------------------------
__global__ __launch_bounds__(256)
void cvt_k(const float* __restrict__ in, bf16* __restrict__ o)
{
  const int i = (blockIdx.x * 256 + threadIdx.x) * 8;
  float4 a = *(const float4*)(in + i);
  float4 b = *(const float4*)(in + i + 4);
  union { bf16 h[8]; s16x8 v; } u;
  u.h[0] = cvt_bf(a.x); u.h[1] = cvt_bf(a.y); u.h[2] = cvt_bf(a.z); u.h[3] = cvt_bf(a.w);
  u.h[4] = cvt_bf(b.x); u.h[5] = cvt_bf(b.y); u.h[6] = cvt_bf(b.z); u.h[7] = cvt_bf(b.w);
  *(s16x8*)(o + i) = u.v;
}

// ---------------------------------------------------------------------------
// Fallback-path weight transpose
// ---------------------------------------------------------------------------
__global__ __launch_bounds__(256)
void wcvt_all_k(const float* __restrict__ wq, const float* __restrict__ wk,
                const float* __restrict__ wv, const float* __restrict__ wo,
                const float* __restrict__ w1, const float* __restrict__ w2,
                bf16* __restrict__ wqkvT, bf16* __restrict__ woT,
                bf16* __restrict__ w1T, bf16* __restrict__ w2T)
{
  __shared__ float tl[32][33];
  const int bid = blockIdx.x;
  const float* W; bf16* Wt; int K, N, tile;
  if (bid < 768)        { int s = bid >> 8; W = s==0?wq:(s==1?wk:wv);
                          Wt = wqkvT + s*262144; K = 512; N = 512; tile = bid & 255; }
  else if (bid < 1024)  { W = wo; Wt = woT; K = 512;  N = 512;  tile = bid - 768; }
  else if (bid < 1536)  { W = w1; Wt = w1T; K = 512;  N = 1024; tile = bid - 1024; }
  else                  { W = w2; Wt = w2T; K = 1024; N = 512;  tile = bid - 1536; }
  const int nx = N >> 5;
  const int n0 = (tile % nx) * 32, k0 = (tile / nx) * 32;
  const int tx = threadIdx.x & 31, ty = threadIdx.x >> 5;
#pragma unroll
  for (int i = 0; i < 32; i += 8)
    tl[ty + i][tx] = W[(size_t)(k0 + ty + i) * N + n0 + tx];
  __syncthreads();
#pragma unroll
  for (int i = 0; i < 32; i += 8)
    Wt[(size_t)(n0 + ty + i) * K + k0 + tx] = cvt_bf(tl[tx][ty + i]);
}

// ---------------------------------------------------------------------------
// GEMM: C = A[8192][K] @ Bt[rows][K]^T, bf16 out. 128xBN tile, BK=64, 4 waves.
// Swapped accumulation (acc = MFMA(bfr, af)) -> packed 8B C-stores.
// EPI 0: QKV merged, V written transposed; EPI 1: +f32 resid; EPI 2: +relu;
// EPI 3: +bf16 resid.
// ---------------------------------------------------------------------------
template<int BN, int EPI>
__global__ __launch_bounds__(256, 2)
void gemm_k(const bf16* __restrict__ A, const bf16* __restrict__ Bt,
            const float* __restrict__ b0, const float* __restrict__ b1,
            const float* __restrict__ b2,
            const float* __restrict__ rF, const bf16* __restrict__ rB,
            bf16* __restrict__ C0, bf16* __restrict__ C1, bf16* __restrict__ C2,
            int Nout, int K)
{
  constexpr int NI = BN / 32;
  __shared__ bf16 As[128 * 64];
  __shared__ bf16 Bs[BN * 64];
  const int tid = threadIdx.x;
  const int wave = tid >> 6, lane = tid & 63;
  const int g = lane >> 4, c = lane & 15;
  const int wgid = blockIdx.x;
  const int xcd = wgid & 7, idx = wgid >> 3;
  const int m0 = (xcd * 8 + (idx & 7)) * 128;
  const int n0 = (idx >> 3) * BN;
  const int wm = (wave >> 1) * 64, wn = (wave & 1) * (BN / 2);
  const int srl = lane >> 3;
  const int csub = ((lane & 7) ^ (lane >> 3)) * 8;

  f32x4 acc[4][NI];
#pragma unroll
  for (int i = 0; i < 4; ++i)
#pragma unroll
    for (int j = 0; j < NI; ++j) acc[i][j] = (f32x4)0.f;

  for (int k0 = 0; k0 < K; k0 += 64) {
#pragma unroll
    for (int is = 0; is < 4; ++is) {
      const int tr = wave * 32 + is * 8;
      g2l16(A + (size_t)(m0 + tr + srl) * K + (k0 + csub), As + tr * 64);
    }
#pragma unroll
    for (int is = 0; is < BN / 32; ++is) {
      const int tr = wave * (BN / 4) + is * 8;
      g2l16(Bt + (size_t)(n0 + tr + srl) * K + (k0 + csub), Bs + tr * 64);
    }
    __syncthreads();
#pragma unroll
    for (int ks = 0; ks < 2; ++ks) {
      s16x8 af[4], bfr[NI];
#pragma unroll
      for (int i = 0; i < 4; ++i) {
        const int ar = wm + i * 16 + c;
        af[i] = *(const s16x8*)((const char*)As + ar * 128 + ((ks * 4 + g) ^ (ar & 7)) * 16);
      }
#pragma unroll
      for (int i = 0; i < NI; ++i) {
        const int br = wn + i * 16 + c;
        bfr[i] = *(const s16x8*)((const char*)Bs + br * 128 + ((ks * 4 + g) ^ (br & 7)) * 16);
      }
#pragma unroll
      for (int mi = 0; mi < 4; ++mi)
#pragma unroll
        for (int ni = 0; ni < NI; ++ni)
          acc[mi][ni] = MFMA(bfr[ni], af[mi], acc[mi][ni]);
    }
    __syncthreads();
  }

  bf16* Cp; const float* bp; int colbase; int vseg = 0;
  if constexpr (EPI == 0) {
    const int seg = n0 >> 9;
    Cp = seg == 0 ? C0 : (seg == 1 ? C1 : C2);
    bp = seg == 0 ? b0 : (seg == 1 ? b1 : b2);
    colbase = n0 & 511;
    vseg = (seg == 2);
  } else { Cp = C0; bp = b0; colbase = n0; }

#pragma unroll
  for (int mi = 0; mi < 4; ++mi) {
    const int row = m0 + wm + mi * 16 + c;
#pragma unroll
    for (int ni = 0; ni < NI; ++ni) {
      const int colb = colbase + wn + ni * 16 + g * 4;
      f32x4 v = acc[mi][ni];
      const f32x4 bv = *(const f32x4*)(bp + colb);
#pragma unroll
      for (int r = 0; r < 4; ++r) v[r] += bv[r];
      if constexpr (EPI == 1) {
        const f32x4 rv = *(const f32x4*)(rF + (size_t)row * Nout + colb);
#pragma unroll
        for (int r = 0; r < 4; ++r) v[r] += rv[r];
      }
      if constexpr (EPI == 2) {
#pragma unroll
        for (int r = 0; r < 4; ++r) v[r] = fmaxf(v[r], 0.f);
      }
      if constexpr (EPI == 3) {
        union { s16x4 x; bf16 h[4]; } rb;
        rb.x = *(const s16x4*)(rB + (size_t)row * Nout + colb);
#pragma unroll
        for (int r = 0; r < 4; ++r) v[r] += bf2f(rb.h[r]);
      }
      union { bf16 h[4]; s16x4 x; } o;
#pragma unroll
      for (int r = 0; r < 4; ++r) o.h[r] = cvt_bf(v[r]);
      if constexpr (EPI == 0) {
        if (vseg) {
          const int bh = (row >> 10) * 8 + (colb >> 6);
          const int dd = colb & 63, kk2 = row & 1023;
          bf16* vp = Cp + (size_t)bh * 65536 + (size_t)dd * 1024 + kk2;
#pragma unroll
          for (int r = 0; r < 4; ++r) vp[r * 1024] = o.h[r];
        } else {
          *(s16x4*)(Cp + (size_t)row * Nout + colb) = o.x;
        }
      } else {
        *(s16x4*)(Cp + (size_t)row * Nout + colb) = o.x;
      }
    }
  }
}

// ---------------------------------------------------------------------------
// Fused GEMM (+bias +bf16 resid) + LayerNorm over the full N=512 row.
// BM=32 x BN=512, 512 threads (8 waves x 64 cols), K in 64-chunks.
// OUTF=0: write bf16 (out-proj+LN1 -> x1b); OUTF=1: write f32 (FFN2+LN2 -> out).
// Row sums: per-lane partials -> shfl_xor(16,32) -> 8-wave LDS reduce.
// ---------------------------------------------------------------------------
template<int OUTF>
__global__ __launch_bounds__(512, 1)
void gemmln_k(const bf16* __restrict__ A, const bf16* __restrict__ Bt,
              const float* __restrict__ bias, const bf16* __restrict__ resid,
              const float* __restrict__ gamma, const float* __restrict__ beta,
              bf16* __restrict__ outb, float* __restrict__ outf, int K)
{
  __shared__ bf16 As[32 * 64];
  __shared__ bf16 Bs[512 * 64];
  __shared__ float redS[2][8][16], redQ[2][8][16];
  const int tid = threadIdx.x;
  const int wave = tid >> 6, lane = tid & 63;
  const int g = lane >> 4, c = lane & 15;
  const int bid = blockIdx.x;
  const int xcd = bid & 7, idx = bid >> 3;
  const int m0 = (xcd * 32 + idx) * 32;        // 32 m-tiles per XCD, contiguous
  const int wn = wave * 64;
  const int rl = lane >> 3;
  const int csub = ((lane & 7) ^ rl) * 8;

  f32x4 acc[2][4];
#pragma unroll
  for (int i = 0; i < 2; ++i)
#pragma unroll
    for (int j = 0; j < 4; ++j) acc[i][j] = (f32x4)0.f;

  for (int k0 = 0; k0 < K; k0 += 64) {
    if (wave < 4)
      g2l16(A + (size_t)(m0 + wave * 8 + rl) * K + (k0 + csub), As + wave * 8 * 64);
#pragma unroll
    for (int is = 0; is < 8; ++is) {
      const int tr = wn + is * 8;
      g2l16(Bt + (size_t)(tr + rl) * K + (k0 + csub), Bs + tr * 64);
    }
    __syncthreads();
#pragma unroll
    for (int ks = 0; ks < 2; ++ks) {
      s16x8 af[2], bfr[4];
#pragma unroll
      for (int i = 0; i < 2; ++i) {
        const int ar = i * 16 + c;
        af[i] = *(const s16x8*)((const char*)As + ar * 128 + ((ks * 4 + g) ^ (ar & 7)) * 16);
      }
#pragma unroll
      for (int i = 0; i < 4; ++i) {
        const int br = wn + i * 16 + c;
        bfr[i] = *(const s16x8*)((const char*)Bs + br * 128 + ((ks * 4 + g) ^ (br & 7)) * 16);
      }
#pragma unroll
      for (int mi = 0; mi < 2; ++mi)
#pragma unroll
        for (int ni = 0; ni < 4; ++ni)
          acc[mi][ni] = MFMA(bfr[ni], af[mi], acc[mi][ni]);
    }
    __syncthreads();
  }

  // epilogue: bias + resid, keep values in regs, per-row partial sums
  float vv[2][4][4];
  float sP[2], qP[2];
#pragma unroll
  for (int mi = 0; mi < 2; ++mi) {
    sP[mi] = 0.f; qP[mi] = 0.f;
    const int row = m0 + mi * 16 + c;
#pragma unroll
    for (int ni = 0; ni < 4; ++ni) {
      const int colb = wn + ni * 16 + g * 4;
      const f32x4 bv = *(const f32x4*)(bias + colb);
      union { s16x4 x; bf16 h[4]; } rb;
      rb.x = *(const s16x4*)(resid + (size_t)row * 512 + colb);
#pragma unroll
      for (int r = 0; r < 4; ++r) {
        const float v = acc[mi][ni][r] + bv[r] + bf2f(rb.h[r]);
        vv[mi][ni][r] = v;
        sP[mi] += v;
        qP[mi] += v * v;
      }
    }
    // butterfly over g (lane bits 4,5): all lanes get wave-total for (mi,c)
    sP[mi] += __shfl_xor(sP[mi], 16); qP[mi] += __shfl_xor(qP[mi], 16);
    sP[mi] += __shfl_xor(sP[mi], 32); qP[mi] += __shfl_xor(qP[mi], 32);
  }
  if (g == 0) {
#pragma unroll
    for (int mi = 0; mi < 2; ++mi) { redS[mi][wave][c] = sP[mi]; redQ[mi][wave][c] = qP[mi]; }
  }
  __syncthreads();

#pragma unroll
  for (int mi = 0; mi < 2; ++mi) {
    float s = 0.f, q = 0.f;
#pragma unroll
    for (int w = 0; w < 8; ++w) { s += redS[mi][w][c]; q += redQ[mi][w][c]; }
    const float mu = s * (1.f / 512.f);
    const float var = q * (1.f / 512.f) - mu * mu;
    const float rs = rsqrtf(var + 1e-5f);
    const int row = m0 + mi * 16 + c;
#pragma unroll
    for (int ni = 0; ni < 4; ++ni) {
      const int colb = wn + ni * 16 + g * 4;
      const f32x4 g4 = *(const f32x4*)(gamma + colb);
      const f32x4 b4 = *(const f32x4*)(beta + colb);
      if constexpr (OUTF) {
        float4 o;
        o.x = (vv[mi][ni][0] - mu) * rs * g4[0] + b4[0];
        o.y = (vv[mi][ni][1] - mu) * rs * g4[1] + b4[1];
        o.z = (vv[mi][ni][2] - mu) * rs * g4[2] + b4[2];
        o.w = (vv[mi][ni][3] - mu) * rs * g4[3] + b4[3];
        *(float4*)(outf + (size_t)row * 512 + colb) = o;
      } else {
        union { bf16 h[4]; s16x4 x; } o;
#pragma unroll
        for (int r = 0; r < 4; ++r)
          o.h[r] = cvt_bf((vv[mi][ni][r] - mu) * rs * g4[r] + b4[r]);
        *(s16x4*)(outb + (size_t)row * 512 + colb) = o.x;
      }
    }
  }
}

// ---------------------------------------------------------------------------
// Attention v2 (register-resident P) — unchanged (validated rounds 5-7).
// ---------------------------------------------------------------------------
__global__ __launch_bounds__(256, 2)
void attn_k(const bf16* __restrict__ Q, const bf16* __restrict__ Kp,
            const bf16* __restrict__ Vt, const int* __restrict__ mask,
            bf16* __restrict__ ctx)
{
  __shared__ bf16 Ks[2][64 * 64];
  __shared__ bf16 Vs[2][64 * 64];
  __shared__ __align__(16) float koff[1024];
  const int lane = threadIdx.x & 63, wave = threadIdx.x >> 6;
  const int g = lane >> 4, c = lane & 15;
  const int wg = blockIdx.x;
  const int swz = (wg & 7) * 64 + (wg >> 3);
  const int qb = swz & 7, bh = swz >> 3;
  const int q0w = qb * 128 + wave * 32;
  const bf16* Qg = Q  + (size_t)bh * 65536;
  const bf16* Kg = Kp + (size_t)bh * 65536;
  const bf16* Vg = Vt + (size_t)bh * 65536;
  const int* mrow = mask + (bh & 7) * 1024;

  {
    const int i = threadIdx.x * 4;
    int4 m4 = *(const int4*)(mrow + i);
    f32x4 kv;
    kv[0] = m4.x ? 0.f : -1e30f;
    kv[1] = m4.y ? 0.f : -1e30f;
    kv[2] = m4.z ? 0.f : -1e30f;
    kv[3] = m4.w ? 0.f : -1e30f;
    *(f32x4*)&koff[i] = kv;
  }

  s16x8 qa[2][2];
#pragma unroll
  for (int qs = 0; qs < 2; ++qs)
#pragma unroll
    for (int h = 0; h < 2; ++h)
      qa[qs][h] = *(const s16x8*)(Qg + (size_t)(q0w + qs * 16 + c) * 64 + h * 32 + g * 8);

  float qm[2][4];
#pragma unroll
  for (int qs = 0; qs < 2; ++qs)
#pragma unroll
    for (int r = 0; r < 4; ++r)
      qm[qs][r] = mrow[q0w + qs * 16 + g * 4 + r] ? 1.f : 0.f;

  s16x8 ones;
#pragma unroll
  for (int i = 0; i < 8; ++i) ones[i] = (short)0x3F80;

  f32x4 acc[2][4], asum[2];
#pragma unroll
  for (int qs = 0; qs < 2; ++qs) {
    asum[qs] = (f32x4)0.f;
#pragma unroll
    for (int db = 0; db < 4; ++db) acc[qs][db] = (f32x4)0.f;
  }

  const int rl = lane >> 3, ch = lane & 7;
  const int schunk = (ch ^ rl) * 8;

  auto STAGE = [&](int kt, int buf) {
#pragma unroll
    for (int rnd = 0; rnd < 2; ++rnd) {
      const int rb = wave * 16 + rnd * 8;
      const int l = rb + rl;
      const int i16 = l & 15, kbb = l >> 4;
      const int srow = ((kbb >> 1) << 5) + ((i16 >> 2) << 3) + ((kbb & 1) << 2) + (i16 & 3);
      g2l16(Kg + (size_t)(kt * 64 + srow) * 64 + schunk, &Ks[buf][rb * 64]);
      g2l16(Vg + (size_t)l * 1024 + kt * 64 + schunk, &Vs[buf][rb * 64]);
    }
  };

  STAGE(0, 0);
  __syncthreads();

  for (int kt = 0; kt < 16; ++kt) {
    const int cur = kt & 1;
    if (kt < 15) STAGE(kt + 1, cur ^ 1);

    union { unsigned w[8]; s16x8 v[2]; } pr[2];

#pragma unroll
    for (int kb = 0; kb < 4; ++kb) {
      const int krow = kb * 16 + c;
      const char* kbase = (const char*)&Ks[cur][0] + krow * 128;
      const s16x8 kf0 = *(const s16x8*)(kbase + ((g    ) ^ (c & 7)) * 16);
      const s16x8 kf1 = *(const s16x8*)(kbase + ((g + 4) ^ (c & 7)) * 16);
      const f32x4 ko = *(const f32x4*)&koff[kt * 64 + ((kb >> 1) << 5) + (g << 3) + ((kb & 1) << 2)];
#pragma unroll
      for (int qs = 0; qs < 2; ++qs) {
        f32x4 z = (f32x4)0.f;
        z = MFMA(kf0, qa[qs][0], z);
        z = MFMA(kf1, qa[qs][1], z);
        union { bf16 h[4]; unsigned u[2]; } eh;
#pragma unroll
        for (int r = 0; r < 4; ++r)
          eh.h[r] = cvt_bf(__expf(fmaf(z[r], 0.125f, ko[r])));
        pr[qs].w[kb * 2]     = eh.u[0];
        pr[qs].w[kb * 2 + 1] = eh.u[1];
      }
    }

#pragma unroll
    for (int kk = 0; kk < 2; ++kk) {
      s16x8 vf[4];
#pragma unroll
      for (int db = 0; db < 4; ++db)
        vf[db] = *(const s16x8*)((const char*)&Vs[cur][0] + (db * 16 + c) * 128 + ((4 * kk + g) ^ (c & 7)) * 16);
#pragma unroll
      for (int qs = 0; qs < 2; ++qs) {
        const s16x8 pa = pr[qs].v[kk];
        asum[qs] = MFMA(pa, ones, asum[qs]);
#pragma unroll
        for (int db = 0; db < 4; ++db)
          acc[qs][db] = MFMA(pa, vf[db], acc[qs][db]);
      }
    }
    __syncthreads();
  }

#pragma unroll
  for (int qs = 0; qs < 2; ++qs)
#pragma unroll
    for (int r = 0; r < 4; ++r) {
      const float inv = qm[qs][r] / fmaxf(asum[qs][r], 1.f);
      const size_t qr = q0w + qs * 16 + g * 4 + r;
#pragma unroll
      for (int db = 0; db < 4; ++db)
        ctx[(size_t)bh * 65536 + qr * 64 + db * 16 + c] = cvt_bf(acc[qs][db][r] * inv);
    }
}

// ---------------------------------------------------------------------------
// LayerNorm D=512 (fallback path only).
// ---------------------------------------------------------------------------
template<int INB, int OUTF, int OUTB>
__global__ __launch_bounds__(256)
void ln_k(const void* __restrict__ xin, const float* __restrict__ g,
          const float* __restrict__ bb, float* __restrict__ of, bf16* __restrict__ ob)
{
  const int row = blockIdx.x * 4 + (threadIdx.x >> 6);
  const int lane = threadIdx.x & 63;
  float xv[8];
  if constexpr (INB) {
    union { s16x8 v; bf16 h[8]; } u;
    u.v = *(const s16x8*)((const bf16*)xin + (size_t)row * 512 + lane * 8);
#pragma unroll
    for (int j = 0; j < 8; ++j) xv[j] = bf2f(u.h[j]);
  } else {
    const float* xr = (const float*)xin + (size_t)row * 512 + lane * 8;
    float4 a = *(const float4*)xr, b = *(const float4*)(xr + 4);
    xv[0]=a.x; xv[1]=a.y; xv[2]=a.z; xv[3]=a.w; xv[4]=b.x; xv[5]=b.y; xv[6]=b.z; xv[7]=b.w;
  }
  float s = 0.f, q = 0.f;
#pragma unroll
  for (int j = 0; j < 8; ++j) { s += xv[j]; q += xv[j] * xv[j]; }
#pragma unroll
  for (int m = 1; m < 64; m <<= 1) { s += __shfl_xor(s, m); q += __shfl_xor(q, m); }
  const float mu = s * (1.f / 512.f);
  const float var = q * (1.f / 512.f) - mu * mu;
  const float rs = rsqrtf(var + 1e-5f);
  float4 g0 = *(const float4*)(g + lane * 8),  g1 = *(const float4*)(g + lane * 8 + 4);
  float4 b0 = *(const float4*)(bb + lane * 8), b1 = *(const float4*)(bb + lane * 8 + 4);
  float gv[8] = {g0.x, g0.y, g0.z, g0.w, g1.x, g1.y, g1.z, g1.w};
  float bv[8] = {b0.x, b0.y, b0.z, b0.w, b1.x, b1.y, b1.z, b1.w};
  float ov[8];
#pragma unroll
  for (int j = 0; j < 8; ++j) ov[j] = (xv[j] - mu) * rs * gv[j] + bv[j];
  if constexpr (OUTF) {
    float4 o0 = {ov[0], ov[1], ov[2], ov[3]};
    float4 o1 = {ov[4], ov[5], ov[6], ov[7]};
    float* outr = of + (size_t)row * 512 + lane * 8;
    *(float4*)outr = o0;
    *(float4*)(outr + 4) = o1;
  }
  if constexpr (OUTB) {
    union { bf16 h[8]; s16x8 v; } u;
#pragma unroll
    for (int j = 0; j < 8; ++j) u.h[j] = cvt_bf(ov[j]);
    *(s16x8*)(ob + (size_t)row * 512 + lane * 8) = u.v;
  }
}

// ---------------------------------------------------------------------------
__global__ __launch_bounds__(256)
void mask_k(const int* __restrict__ m, float* __restrict__ out)
{
  const int i = blockIdx.x * 256 + threadIdx.x;
  const float v = (float)m[i];
  out[4194304 + i] = v;
  out[12591104 + i] = v;
}

// ---------------------------------------------------------------------------
extern "C" void kernel_launch(void* const* d_in, const int* in_sizes, int n_in,
                              void* d_out, int out_size, void* d_ws, size_t ws_size,
                              hipStream_t stream)
{
  const float* query = (const float*)d_in[0];
  const int*   qmask = (const int*)d_in[1];
  const float* wq = (const float*)d_in[2];
  const float* bq = (const float*)d_in[3];
  const float* wk = (const float*)d_in[4];
  const float* bk = (const float*)d_in[5];
  const float* wv = (const float*)d_in[6];
  const float* bv = (const float*)d_in[7];
  const float* wo = (const float*)d_in[8];
  const float* bo = (const float*)d_in[9];
  const float* ln1g = (const float*)d_in[10];
  const float* ln1b = (const float*)d_in[11];
  const float* w1 = (const float*)d_in[12];
  const float* b1 = (const float*)d_in[13];
  const float* w2 = (const float*)d_in[14];
  const float* b2 = (const float*)d_in[15];
  const float* ln2g = (const float*)d_in[16];
  const float* ln2b = (const float*)d_in[17];
  float* out = (float*)d_out;
  char* ws = (char*)d_ws;

  bf16* wqkvT = (bf16*)(ws);              // [1536][512]
  bf16* woT   = (bf16*)(ws + 1572864);    // [512][512]
  bf16* w1T   = (bf16*)(ws + 2097152);    // [1024][512]
  bf16* w2T   = (bf16*)(ws + 3145728);    // [512][1024]

  const dim3 blk(256);

  if (ws_size >= (size_t)96468992) {
    // ---------- big-workspace path ----------
    bf16*  qb    = (bf16*)(ws + 4194304);
    bf16*  Qb    = (bf16*)(ws + 12582912);
    bf16*  Kb    = (bf16*)(ws + 20971520);
    bf16*  VtG   = (bf16*)(ws + 37748736);
    bf16*  ctx   = (bf16*)(ws + 46137344);
    bf16*  x1b   = (bf16*)(ws + 62914560);
    bf16*  hbuf  = (bf16*)(ws + 71303168);

    prep2_k<<<4128, blk, 0, stream>>>(query, qmask, wq, wk, wv, wo, w1, w2,
                                      wqkvT, woT, w1T, w2T, qb, out);
    gemm_k<128, 0><<<768, blk, 0, stream>>>(qb, wqkvT, bq, bk, bv,
        nullptr, nullptr, Qb, Kb, VtG, 512, 512);
    attn_k<<<512, blk, 0, stream>>>(Qb, Kb, VtG, qmask, ctx);
    // out-proj + bias + bf16 resid(qb) + LN1 -> x1b (bf16)
    gemmln_k<0><<<256, dim3(512), 0, stream>>>(ctx, woT, bo, qb, ln1g, ln1b,
                                               x1b, nullptr, 512);
    gemm_k<128, 2><<<512, blk, 0, stream>>>(x1b, w1T, b1, nullptr, nullptr,
        nullptr, nullptr, hbuf, nullptr, nullptr, 1024, 512);
    // FFN2 + bias + bf16 resid(x1b) + LN2 -> out (f32, final)
    gemmln_k<1><<<256, dim3(512), 0, stream>>>(hbuf, w2T, b2, x1b, ln2g, ln2b,
                                               nullptr, out, 1024);
  } else {
    // ---------- fallback: d_out-aliased scratch (round-5 proven layout) ----------
    char* ob = (char*)d_out;
    char* R0 = ob;
    char* R1 = ob + 16809984;
    char* R2 = ob + 33587200;
    bf16*  qb    = (bf16*)R0;
    bf16*  ctx   = (bf16*)R0;
    bf16*  x1b   = (bf16*)R0;
    bf16*  Qb    = (bf16*)R1;
    bf16*  Kb    = (bf16*)(R1 + 8388608);
    bf16*  attnr = (bf16*)R1;
    bf16*  hbuf  = (bf16*)R1;
    bf16*  VtG   = (bf16*)(R2 + 8388608);
    bf16*  ybuf  = (bf16*)R2;

    wcvt_all_k<<<2048, blk, 0, stream>>>(wq, wk, wv, wo, w1, w2, wqkvT, woT, w1T, w2T);
    cvt_k<<<2048, blk, 0, stream>>>(query, qb);
    gemm_k<128, 0><<<768, blk, 0, stream>>>(qb, wqkvT, bq, bk, bv,
        nullptr, nullptr, Qb, Kb, VtG, 512, 512);
    attn_k<<<512, blk, 0, stream>>>(Qb, Kb, VtG, qmask, ctx);
    gemm_k<64, 1><<<512, blk, 0, stream>>>(ctx, woT, bo, nullptr, nullptr,
        query, nullptr, attnr, nullptr, nullptr, 512, 512);
    ln_k<1, 0, 1><<<2048, blk, 0, stream>>>(attnr, ln1g, ln1b, nullptr, x1b);
    gemm_k<128, 2><<<512, blk, 0, stream>>>(x1b, w1T, b1, nullptr, nullptr,
        nullptr, nullptr, hbuf, nullptr, nullptr, 1024, 512);
    gemm_k<64, 3><<<512, blk, 0, stream>>>(hbuf, w2T, b2, nullptr, nullptr,
        nullptr, x1b, ybuf, nullptr, nullptr, 512, 1024);
    ln_k<1, 1, 0><<<2048, blk, 0, stream>>>(ybuf, ln2g, ln2b, out, nullptr);
    mask_k<<<32, blk, 0, stream>>>(qmask, out);
    hipMemcpyAsync(out + 4202496, query, 16777216, hipMemcpyDeviceToDevice, stream);
    hipMemcpyAsync(out + 8396800, query, 16777216, hipMemcpyDeviceToDevice, stream);
  }
}